// Round 5
// baseline (615.856 us; speedup 1.0000x reference)
//
#include <hip/hip_runtime.h>
#include <math.h>

#define N_NODES 50000
#define E_TRAIN 800000
#define E_POS 200000
#define E_NEG 200000

// ---------------- degree / CSR build ----------------

__global__ void count_kernel(const int* __restrict__ dst, int* __restrict__ cnt, int e) {
    int i = blockIdx.x * blockDim.x + threadIdx.x;
    if (i < e) atomicAdd(&cnt[dst[i]], 1);
}

__global__ void dis_kernel(const int* __restrict__ cnt, float* __restrict__ dis, int n) {
    int i = blockIdx.x * blockDim.x + threadIdx.x;
    if (i < n) dis[i] = 1.0f / sqrtf((float)(cnt[i] + 1));  // +1 self loop, deg>=1
}

// block-level exclusive scan (256/block) + block sums
__global__ void scan1_kernel(const int* __restrict__ cnt, int* __restrict__ offs,
                             int* __restrict__ bsum, int n) {
    __shared__ int s[256];
    int i = blockIdx.x * 256 + threadIdx.x;
    int c = (i < n) ? cnt[i] : 0;
    s[threadIdx.x] = c;
    __syncthreads();
    for (int d = 1; d < 256; d <<= 1) {
        int t = 0;
        if ((int)threadIdx.x >= d) t = s[threadIdx.x - d];
        __syncthreads();
        if ((int)threadIdx.x >= d) s[threadIdx.x] += t;
        __syncthreads();
    }
    if (i < n) offs[i] = s[threadIdx.x] - c;  // exclusive
    if (threadIdx.x == 255) bsum[blockIdx.x] = s[255];
}

// parallel exclusive scan of the 196 block sums (single 256-thread block)
__global__ void scan2_kernel(int* __restrict__ bsum, int nb) {
    __shared__ int s[256];
    int t = threadIdx.x;
    int v = (t < nb) ? bsum[t] : 0;
    s[t] = v;
    __syncthreads();
    for (int d = 1; d < 256; d <<= 1) {
        int u = 0;
        if (t >= d) u = s[t - d];
        __syncthreads();
        if (t >= d) s[t] += u;
        __syncthreads();
    }
    if (t < nb) bsum[t] = s[t] - v;  // exclusive
}

__global__ void scan3_kernel(int* __restrict__ offs, const int* __restrict__ bsum,
                             int* __restrict__ cursor, int n) {
    int i = blockIdx.x * 256 + threadIdx.x;   // blockDim must be 256
    if (i < n) { int o = offs[i] + bsum[i >> 8]; offs[i] = o; cursor[i] = o; }
}

__global__ void fill_kernel(const int* __restrict__ src, const int* __restrict__ dst,
                            int* __restrict__ cursor, int* __restrict__ csr_src, int e) {
    int i = blockIdx.x * blockDim.x + threadIdx.x;
    if (i < e) {
        int p = atomicAdd(&cursor[dst[i]], 1);
        csr_src[p] = src[i];
    }
}

// ---------------- fp32 GEMM, lane=row column-serial: C[M,N] = A[M,K] @ B[K,N] ----------------
// 128 threads (2 waves). Block: 128 rows x 64 cols. Lane = row; acc[64] per lane.
// A staged in LDS [row][k], row stride 36 floats (144B: b128-aligned, full-throughput banks).
// B read with wave-uniform addresses (loop indices only) -> compiler scalarizes to s_load;
// B never touches LDS or VGPR-side VMEM. Per k: 64 FMAs vs 0.25 ds_read_b128 -> FMA-bound.
// Requires: N % 64 == 0, K % 32 == 0. M guarded. BR: fused bias+relu epilogue.

#define GSTRIDE 36

template<bool BR>
__global__ __launch_bounds__(128, 4) void gemm_kernel(
        const float* __restrict__ A, const float* __restrict__ B,
        const float* __restrict__ bias, float* __restrict__ C,
        int M, int N, int K) {
    __shared__ float As[128 * GSTRIDE];
    int tid = threadIdx.x;              // 0..127 == row within tile
    int brow = blockIdx.x * 128;
    int bcol = blockIdx.y * 64;
    int myrow = brow + tid;

    float acc[64];
    #pragma unroll
    for (int j = 0; j < 64; j++) acc[j] = 0.f;

    for (int k0 = 0; k0 < K; k0 += 32) {
        // stage A tile: 128 rows x 32 k = 1024 float4, 8 per thread
        #pragma unroll
        for (int p = 0; p < 8; p++) {
            int idx = p * 128 + tid;
            int r = idx >> 3;               // 0..127
            int kc = idx & 7;               // float4 index within 32 k
            int row = brow + r;
            float4 v = make_float4(0.f, 0.f, 0.f, 0.f);
            if (row < M) v = *(const float4*)&A[(size_t)row * K + k0 + kc * 4];
            *(float4*)&As[r * GSTRIDE + kc * 4] = v;
        }
        __syncthreads();
        // inner: per 4 k's, one b128 A-read; B rows are wave-uniform
        for (int kk = 0; kk < 32; kk += 4) {
            float4 a4 = *(const float4*)&As[tid * GSTRIDE + kk];
            float a[4] = {a4.x, a4.y, a4.z, a4.w};
            #pragma unroll
            for (int q = 0; q < 4; q++) {
                const float* Brow = &B[(size_t)(k0 + kk + q) * N + bcol];
                #pragma unroll
                for (int j = 0; j < 64; j++)
                    acc[j] = fmaf(a[q], Brow[j], acc[j]);
            }
        }
        __syncthreads();
    }

    if (myrow < M) {
        float* Crow = &C[(size_t)myrow * N + bcol];
        #pragma unroll
        for (int j = 0; j < 64; j += 4) {
            float t0 = acc[j + 0], t1 = acc[j + 1], t2 = acc[j + 2], t3 = acc[j + 3];
            if (BR) {
                t0 = fmaxf(t0 + bias[bcol + j + 0], 0.f);
                t1 = fmaxf(t1 + bias[bcol + j + 1], 0.f);
                t2 = fmaxf(t2 + bias[bcol + j + 2], 0.f);
                t3 = fmaxf(t3 + bias[bcol + j + 3], 0.f);
            }
            float4 r; r.x = t0; r.y = t1; r.z = t2; r.w = t3;
            *(float4*)&Crow[j] = r;
        }
    }
}

// ---------------- aggregation: out[v] = sum_in h[u]*dis[u]*dis[v] + h[v]*dis[v]^2 (+ b, relu) ----
// one wave per node, lane holds VPT consecutive features (float2 for F=128).
// 8-edge batched main loop: 8 independent index->weight->gather chains in flight.

template<int F, bool RELU, bool BIAS>
__global__ void aggregate_kernel(const float* __restrict__ xw,
                                 float* __restrict__ out,
                                 const float* __restrict__ dis,
                                 const int* __restrict__ starts,
                                 const int* __restrict__ ends,
                                 const int* __restrict__ csr_src,
                                 const float* __restrict__ bias,
                                 int n) {
    int wave = (blockIdx.x * blockDim.x + threadIdx.x) >> 6;
    int lane = threadIdx.x & 63;
    if (wave >= n) return;
    int v = wave;
    constexpr int VPT = F / 64;  // consecutive floats per lane
    float dv = dis[v];
    float acc[VPT];
    {
        const float* r = &xw[(size_t)v * F + lane * VPT];
        #pragma unroll
        for (int i = 0; i < VPT; i++) acc[i] = r[i] * dv * dv;
    }
    int s = starts[v], e = ends[v];
    int p = s;
    for (; p + 8 <= e; p += 8) {
        int u[8];
        #pragma unroll
        for (int q = 0; q < 8; q++) u[q] = csr_src[p + q];
        float w[8];
        #pragma unroll
        for (int q = 0; q < 8; q++) w[q] = dis[u[q]] * dv;
        if constexpr (VPT == 2) {
            float2 g[8];
            #pragma unroll
            for (int q = 0; q < 8; q++)
                g[q] = *(const float2*)&xw[(size_t)u[q] * F + lane * 2];
            #pragma unroll
            for (int q = 0; q < 8; q++) {
                acc[0] += g[q].x * w[q];
                acc[1] += g[q].y * w[q];
            }
        } else {
            float g[8];
            #pragma unroll
            for (int q = 0; q < 8; q++)
                g[q] = xw[(size_t)u[q] * F + lane];
            #pragma unroll
            for (int q = 0; q < 8; q++) acc[0] += g[q] * w[q];
        }
    }
    for (; p < e; p++) {
        int u = csr_src[p];
        float w = dis[u] * dv;
        const float* r = &xw[(size_t)u * F + lane * VPT];
        #pragma unroll
        for (int i = 0; i < VPT; i++) acc[i] += r[i] * w;
    }
    {
        float* o = &out[(size_t)v * F + lane * VPT];
        #pragma unroll
        for (int i = 0; i < VPT; i++) {
            float r = acc[i];
            if (BIAS) r += bias[lane * VPT + i];
            if (RELU) r = fmaxf(r, 0.f);
            o[i] = r;
        }
    }
}

// ---------------- edge dot products: out[e] = h[i0] . h[i1], F=64 ----------------
// thread-per-edge, float4 x 16 per row, fully independent loads.

__global__ void dot_kernel(const float* __restrict__ h,
                           const int* __restrict__ pos, const int* __restrict__ neg,
                           float* __restrict__ out) {
    int t = blockIdx.x * blockDim.x + threadIdx.x;
    if (t >= E_POS + E_NEG) return;
    int i0, i1;
    if (t < E_POS) { i0 = pos[t]; i1 = pos[E_POS + t]; }
    else { int e = t - E_POS; i0 = neg[e]; i1 = neg[E_NEG + e]; }
    const float4* a = (const float4*)&h[(size_t)i0 * 64];
    const float4* b = (const float4*)&h[(size_t)i1 * 64];
    float s0 = 0.f, s1 = 0.f, s2 = 0.f, s3 = 0.f;
    #pragma unroll
    for (int k = 0; k < 16; k += 4) {
        float4 a0 = a[k + 0], a1 = a[k + 1], a2 = a[k + 2], a3 = a[k + 3];
        float4 b0 = b[k + 0], b1 = b[k + 1], b2 = b[k + 2], b3 = b[k + 3];
        s0 += a0.x * b0.x + a0.y * b0.y + a0.z * b0.z + a0.w * b0.w;
        s1 += a1.x * b1.x + a1.y * b1.y + a1.z * b1.z + a1.w * b1.w;
        s2 += a2.x * b2.x + a2.y * b2.y + a2.z * b2.z + a2.w * b2.w;
        s3 += a3.x * b3.x + a3.y * b3.y + a3.z * b3.z + a3.w * b3.w;
    }
    out[t] = (s0 + s1) + (s2 + s3);
}

// ---------------- launch ----------------

extern "C" void kernel_launch(void* const* d_in, const int* in_sizes, int n_in,
                              void* d_out, int out_size, void* d_ws, size_t ws_size,
                              hipStream_t stream) {
    const float* x  = (const float*)d_in[0];
    const int* tei  = (const int*)d_in[1];
    const int* pos  = (const int*)d_in[2];
    const int* neg  = (const int*)d_in[3];
    const float* W1 = (const float*)d_in[4];
    const float* b1 = (const float*)d_in[5];
    const float* W2 = (const float*)d_in[6];
    const float* b2 = (const float*)d_in[7];
    const float* W3 = (const float*)d_in[8];
    const float* b3 = (const float*)d_in[9];
    float* out = (float*)d_out;

    const int* src = tei;
    const int* dst = tei + E_TRAIN;

    char* ws = (char*)d_ws;
    size_t off = 0;
    auto alloc = [&](size_t bytes) -> void* {
        void* p = ws + off;
        off = (off + bytes + 255) & ~(size_t)255;
        return p;
    };
    float* bufA = (float*)alloc((size_t)N_NODES * 128 * 4);  // aggX / xw2 / xw3
    float* bufB = (float*)alloc((size_t)N_NODES * 256 * 4);  // h1, later h3
    float* bufC = (float*)alloc((size_t)N_NODES * 128 * 4);  // h2
    float* dis  = (float*)alloc(N_NODES * 4);
    int* cnt    = (int*)alloc(N_NODES * 4);
    int* offs   = (int*)alloc(N_NODES * 4);
    int* cursor = (int*)alloc(N_NODES * 4);
    int* bsum   = (int*)alloc(256 * 4);
    int* csr    = (int*)alloc((size_t)E_TRAIN * 4);
    (void)ws_size; (void)n_in; (void)in_sizes; (void)out_size;

    hipMemsetAsync(cnt, 0, N_NODES * 4, stream);
    count_kernel<<<(E_TRAIN + 255) / 256, 256, 0, stream>>>(dst, cnt, E_TRAIN);
    dis_kernel<<<(N_NODES + 255) / 256, 256, 0, stream>>>(cnt, dis, N_NODES);
    int nb = (N_NODES + 255) / 256;  // 196
    scan1_kernel<<<nb, 256, 0, stream>>>(cnt, offs, bsum, N_NODES);
    scan2_kernel<<<1, 256, 0, stream>>>(bsum, nb);
    scan3_kernel<<<nb, 256, 0, stream>>>(offs, bsum, cursor, N_NODES);
    fill_kernel<<<(E_TRAIN + 255) / 256, 256, 0, stream>>>(src, dst, cursor, csr, E_TRAIN);
    // after fill: offs[v] = start, cursor[v] = end

    const int MB = (N_NODES + 127) / 128;     // 391 row tiles
    const int AGG_BLOCKS = (N_NODES + 3) / 4; // 4 waves/block, 1 node/wave

    // layer 1 (agg-first): aggX = agg(x) [F=128]; h1 = relu(aggX @ W1 + b1) [256]
    aggregate_kernel<128, false, false><<<AGG_BLOCKS, 256, 0, stream>>>(
        x, bufA, dis, offs, cursor, csr, nullptr, N_NODES);
    gemm_kernel<true><<<dim3(MB, 4), 128, 0, stream>>>(
        bufA, W1, b1, bufB, N_NODES, 256, 128);

    // layer 2 (gemm-first): xw2 = h1 @ W2 [128]; h2 = relu(agg(xw2) + b2)
    gemm_kernel<false><<<dim3(MB, 2), 128, 0, stream>>>(
        bufB, W2, nullptr, bufA, N_NODES, 128, 256);
    aggregate_kernel<128, true, true><<<AGG_BLOCKS, 256, 0, stream>>>(
        bufA, bufC, dis, offs, cursor, csr, b2, N_NODES);

    // layer 3 (gemm-first): xw3 = h2 @ W3 [64]; h3 = agg(xw3) + b3
    gemm_kernel<false><<<dim3(MB, 1), 128, 0, stream>>>(
        bufC, W3, nullptr, bufA, N_NODES, 64, 128);
    aggregate_kernel<64, false, true><<<AGG_BLOCKS, 256, 0, stream>>>(
        bufA, bufB, dis, offs, cursor, csr, b3, N_NODES);

    // edge dots over h3 (64 features)
    dot_kernel<<<(E_POS + E_NEG + 255) / 256, 256, 0, stream>>>(bufB, pos, neg, out);
}

// Round 6
// 453.647 us; speedup vs baseline: 1.3576x; 1.3576x over previous
//
#include <hip/hip_runtime.h>
#include <math.h>

#define N_NODES 50000
#define E_TRAIN 800000
#define E_POS 200000
#define E_NEG 200000

// ---------------- degree / CSR build ----------------

__global__ void count_kernel(const int* __restrict__ dst, int* __restrict__ cnt, int e) {
    int i = blockIdx.x * blockDim.x + threadIdx.x;
    if (i < e) atomicAdd(&cnt[dst[i]], 1);
}

__global__ void dis_kernel(const int* __restrict__ cnt, float* __restrict__ dis, int n) {
    int i = blockIdx.x * blockDim.x + threadIdx.x;
    if (i < n) dis[i] = 1.0f / sqrtf((float)(cnt[i] + 1));  // +1 self loop, deg>=1
}

// block-level exclusive scan (256/block) + block sums
__global__ void scan1_kernel(const int* __restrict__ cnt, int* __restrict__ offs,
                             int* __restrict__ bsum, int n) {
    __shared__ int s[256];
    int i = blockIdx.x * 256 + threadIdx.x;
    int c = (i < n) ? cnt[i] : 0;
    s[threadIdx.x] = c;
    __syncthreads();
    for (int d = 1; d < 256; d <<= 1) {
        int t = 0;
        if ((int)threadIdx.x >= d) t = s[threadIdx.x - d];
        __syncthreads();
        if ((int)threadIdx.x >= d) s[threadIdx.x] += t;
        __syncthreads();
    }
    if (i < n) offs[i] = s[threadIdx.x] - c;  // exclusive
    if (threadIdx.x == 255) bsum[blockIdx.x] = s[255];
}

// parallel exclusive scan of the 196 block sums (single 256-thread block)
__global__ void scan2_kernel(int* __restrict__ bsum, int nb) {
    __shared__ int s[256];
    int t = threadIdx.x;
    int v = (t < nb) ? bsum[t] : 0;
    s[t] = v;
    __syncthreads();
    for (int d = 1; d < 256; d <<= 1) {
        int u = 0;
        if (t >= d) u = s[t - d];
        __syncthreads();
        if (t >= d) s[t] += u;
        __syncthreads();
    }
    if (t < nb) bsum[t] = s[t] - v;  // exclusive
}

__global__ void scan3_kernel(int* __restrict__ offs, const int* __restrict__ bsum,
                             int* __restrict__ cursor, int n) {
    int i = blockIdx.x * 256 + threadIdx.x;   // blockDim must be 256
    if (i < n) { int o = offs[i] + bsum[i >> 8]; offs[i] = o; cursor[i] = o; }
}

__global__ void fill_kernel(const int* __restrict__ src, const int* __restrict__ dst,
                            int* __restrict__ cursor, int* __restrict__ csr_src, int e) {
    int i = blockIdx.x * blockDim.x + threadIdx.x;
    if (i < e) {
        int p = atomicAdd(&cursor[dst[i]], 1);
        csr_src[p] = src[i];
    }
}

// ---------------- split-bf16 helpers ----------------
// f = hi + lo exactly-ish: hi = trunc-to-bf16(f), lo = trunc-to-bf16(f - hi).
// residual <= 2^-16 * |f| -> negligible vs fp32 baseline absmax 2e-3.

__device__ inline void split_bf16(float f, short& h, short& l) {
    unsigned u = __float_as_uint(f);
    h = (short)(u >> 16);
    float rem = f - __uint_as_float(u & 0xFFFF0000u);
    l = (short)(__float_as_uint(rem) >> 16);
}

// W -> transposed hi/lo bf16: Wt[n*K + k] from W[k*N + n]. Tiny, once per call.
__global__ void wsplit_kernel(const float* __restrict__ W,
                              short* __restrict__ Wt_hi, short* __restrict__ Wt_lo,
                              int K, int N) {
    int i = blockIdx.x * blockDim.x + threadIdx.x;
    if (i >= K * N) return;
    int k = i / N, n = i - k * N;
    short h, l;
    split_bf16(W[i], h, l);
    Wt_hi[(size_t)n * K + k] = h;
    Wt_lo[(size_t)n * K + k] = l;
}

// ---------------- MFMA GEMM (split-bf16): C[M,N] = A[M,K] @ B[K,N] ----------------
// 256 threads = 4 waves. Block tile 128x64; wave tile 32x64 as 2x4 16x16 tiles.
// v_mfma_f32_16x16x32_bf16; per useful k-tile: 3 MFMAs (hi*hi + lo*hi + hi*lo).
// A split fp32->bf16 hi/lo during LDS staging. B from precomputed Wt_hi/Wt_lo [N][K].
// LDS row stride 40 shorts (80 B) -> 16B-aligned b128 frag reads, ~2-way banks (free).
// Requires: N % 64 == 0, K % 32 == 0. M guarded. BR: fused bias+relu epilogue.

typedef short bf16x8 __attribute__((ext_vector_type(8)));
typedef float f32x4 __attribute__((ext_vector_type(4)));

#define ASTRIDE 40

template<bool BR>
__global__ __launch_bounds__(256) void gemm_mfma_kernel(
        const float* __restrict__ A,
        const short* __restrict__ Bt_hi, const short* __restrict__ Bt_lo,
        const float* __restrict__ bias, float* __restrict__ C,
        int M, int N, int K) {
    __shared__ short Ahi[128][ASTRIDE];
    __shared__ short Alo[128][ASTRIDE];
    __shared__ short Bhi[64][ASTRIDE];
    __shared__ short Blo[64][ASTRIDE];
    int tid = threadIdx.x;
    int lane = tid & 63;
    int wv = tid >> 6;                 // 0..3
    int brow = blockIdx.x * 128;
    int bcol = blockIdx.y * 64;
    int m_lane = lane & 15;
    int kgrp = lane >> 4;              // 0..3

    f32x4 acc[2][4];
    #pragma unroll
    for (int i = 0; i < 2; i++)
        #pragma unroll
        for (int j = 0; j < 4; j++) acc[i][j] = (f32x4){0.f, 0.f, 0.f, 0.f};

    for (int k0 = 0; k0 < K; k0 += 32) {
        // stage A: 128 rows x 32 k, fp32 -> hi/lo bf16
        #pragma unroll
        for (int p = 0; p < 4; p++) {
            int idx = p * 256 + tid;
            int r = idx >> 3;               // 0..127
            int kc = idx & 7;               // float4 index
            int row = brow + r;
            float4 v = make_float4(0.f, 0.f, 0.f, 0.f);
            if (row < M) v = *(const float4*)&A[(size_t)row * K + k0 + kc * 4];
            short4 h, l;
            split_bf16(v.x, h.x, l.x);
            split_bf16(v.y, h.y, l.y);
            split_bf16(v.z, h.z, l.z);
            split_bf16(v.w, h.w, l.w);
            *(short4*)&Ahi[r][kc * 4] = h;
            *(short4*)&Alo[r][kc * 4] = l;
        }
        // stage B: 64 n x 32 k, contiguous int4 copies from Wt [N][K]
        {
            int n = tid >> 2;               // 0..63
            int kc = tid & 3;               // 0..3 (8 shorts each)
            size_t boff = (size_t)(bcol + n) * K + k0 + kc * 8;
            *(int4*)&Bhi[n][kc * 8] = *(const int4*)&Bt_hi[boff];
            *(int4*)&Blo[n][kc * 8] = *(const int4*)&Bt_lo[boff];
        }
        __syncthreads();

        bf16x8 bh[4], bl[4];
        #pragma unroll
        for (int ni = 0; ni < 4; ni++) {
            bh[ni] = *(const bf16x8*)&Bhi[ni * 16 + m_lane][kgrp * 8];
            bl[ni] = *(const bf16x8*)&Blo[ni * 16 + m_lane][kgrp * 8];
        }
        #pragma unroll
        for (int mi = 0; mi < 2; mi++) {
            int r = wv * 32 + mi * 16 + m_lane;
            bf16x8 ah = *(const bf16x8*)&Ahi[r][kgrp * 8];
            bf16x8 al = *(const bf16x8*)&Alo[r][kgrp * 8];
            #pragma unroll
            for (int ni = 0; ni < 4; ni++) {
                acc[mi][ni] = __builtin_amdgcn_mfma_f32_16x16x32_bf16(ah, bh[ni], acc[mi][ni], 0, 0, 0);
                acc[mi][ni] = __builtin_amdgcn_mfma_f32_16x16x32_bf16(al, bh[ni], acc[mi][ni], 0, 0, 0);
                acc[mi][ni] = __builtin_amdgcn_mfma_f32_16x16x32_bf16(ah, bl[ni], acc[mi][ni], 0, 0, 0);
            }
        }
        __syncthreads();
    }

    // epilogue: C/D layout col = lane&15, row = (lane>>4)*4 + reg
    #pragma unroll
    for (int ni = 0; ni < 4; ni++) {
        int col = bcol + ni * 16 + m_lane;
        float bb = 0.f;
        if (BR) bb = bias[col];
        #pragma unroll
        for (int mi = 0; mi < 2; mi++) {
            int rbase = brow + wv * 32 + mi * 16 + kgrp * 4;
            #pragma unroll
            for (int reg = 0; reg < 4; reg++) {
                int row = rbase + reg;
                if (row < M) {
                    float v = acc[mi][ni][reg];
                    if (BR) v = fmaxf(v + bb, 0.f);
                    C[(size_t)row * N + col] = v;
                }
            }
        }
    }
}

// ---------------- aggregation: out[v] = sum_in h[u]*dis[u]*dis[v] + h[v]*dis[v]^2 (+ b, relu) ----
// one wave per node, lane holds VPT consecutive features (float2 for F=128).
// 8-edge batched main loop: 8 independent index->weight->gather chains in flight.

template<int F, bool RELU, bool BIAS>
__global__ void aggregate_kernel(const float* __restrict__ xw,
                                 float* __restrict__ out,
                                 const float* __restrict__ dis,
                                 const int* __restrict__ starts,
                                 const int* __restrict__ ends,
                                 const int* __restrict__ csr_src,
                                 const float* __restrict__ bias,
                                 int n) {
    int wave = (blockIdx.x * blockDim.x + threadIdx.x) >> 6;
    int lane = threadIdx.x & 63;
    if (wave >= n) return;
    int v = wave;
    constexpr int VPT = F / 64;  // consecutive floats per lane
    float dv = dis[v];
    float acc[VPT];
    {
        const float* r = &xw[(size_t)v * F + lane * VPT];
        #pragma unroll
        for (int i = 0; i < VPT; i++) acc[i] = r[i] * dv * dv;
    }
    int s = starts[v], e = ends[v];
    int p = s;
    for (; p + 8 <= e; p += 8) {
        int u[8];
        #pragma unroll
        for (int q = 0; q < 8; q++) u[q] = csr_src[p + q];
        float w[8];
        #pragma unroll
        for (int q = 0; q < 8; q++) w[q] = dis[u[q]] * dv;
        if constexpr (VPT == 2) {
            float2 g[8];
            #pragma unroll
            for (int q = 0; q < 8; q++)
                g[q] = *(const float2*)&xw[(size_t)u[q] * F + lane * 2];
            #pragma unroll
            for (int q = 0; q < 8; q++) {
                acc[0] += g[q].x * w[q];
                acc[1] += g[q].y * w[q];
            }
        } else {
            float g[8];
            #pragma unroll
            for (int q = 0; q < 8; q++)
                g[q] = xw[(size_t)u[q] * F + lane];
            #pragma unroll
            for (int q = 0; q < 8; q++) acc[0] += g[q] * w[q];
        }
    }
    for (; p < e; p++) {
        int u = csr_src[p];
        float w = dis[u] * dv;
        const float* r = &xw[(size_t)u * F + lane * VPT];
        #pragma unroll
        for (int i = 0; i < VPT; i++) acc[i] += r[i] * w;
    }
    {
        float* o = &out[(size_t)v * F + lane * VPT];
        #pragma unroll
        for (int i = 0; i < VPT; i++) {
            float r = acc[i];
            if (BIAS) r += bias[lane * VPT + i];
            if (RELU) r = fmaxf(r, 0.f);
            o[i] = r;
        }
    }
}

// ---------------- edge dot products: out[e] = h[i0] . h[i1], F=64 ----------------
// thread-per-edge, float4 x 16 per row, fully independent loads.

__global__ void dot_kernel(const float* __restrict__ h,
                           const int* __restrict__ pos, const int* __restrict__ neg,
                           float* __restrict__ out) {
    int t = blockIdx.x * blockDim.x + threadIdx.x;
    if (t >= E_POS + E_NEG) return;
    int i0, i1;
    if (t < E_POS) { i0 = pos[t]; i1 = pos[E_POS + t]; }
    else { int e = t - E_POS; i0 = neg[e]; i1 = neg[E_NEG + e]; }
    const float4* a = (const float4*)&h[(size_t)i0 * 64];
    const float4* b = (const float4*)&h[(size_t)i1 * 64];
    float s0 = 0.f, s1 = 0.f, s2 = 0.f, s3 = 0.f;
    #pragma unroll
    for (int k = 0; k < 16; k += 4) {
        float4 a0 = a[k + 0], a1 = a[k + 1], a2 = a[k + 2], a3 = a[k + 3];
        float4 b0 = b[k + 0], b1 = b[k + 1], b2 = b[k + 2], b3 = b[k + 3];
        s0 += a0.x * b0.x + a0.y * b0.y + a0.z * b0.z + a0.w * b0.w;
        s1 += a1.x * b1.x + a1.y * b1.y + a1.z * b1.z + a1.w * b1.w;
        s2 += a2.x * b2.x + a2.y * b2.y + a2.z * b2.z + a2.w * b2.w;
        s3 += a3.x * b3.x + a3.y * b3.y + a3.z * b3.z + a3.w * b3.w;
    }
    out[t] = (s0 + s1) + (s2 + s3);
}

// ---------------- launch ----------------

extern "C" void kernel_launch(void* const* d_in, const int* in_sizes, int n_in,
                              void* d_out, int out_size, void* d_ws, size_t ws_size,
                              hipStream_t stream) {
    const float* x  = (const float*)d_in[0];
    const int* tei  = (const int*)d_in[1];
    const int* pos  = (const int*)d_in[2];
    const int* neg  = (const int*)d_in[3];
    const float* W1 = (const float*)d_in[4];
    const float* b1 = (const float*)d_in[5];
    const float* W2 = (const float*)d_in[6];
    const float* b2 = (const float*)d_in[7];
    const float* W3 = (const float*)d_in[8];
    const float* b3 = (const float*)d_in[9];
    float* out = (float*)d_out;

    const int* src = tei;
    const int* dst = tei + E_TRAIN;

    char* ws = (char*)d_ws;
    size_t off = 0;
    auto alloc = [&](size_t bytes) -> void* {
        void* p = ws + off;
        off = (off + bytes + 255) & ~(size_t)255;
        return p;
    };
    float* bufA = (float*)alloc((size_t)N_NODES * 128 * 4);  // aggX / xw2 / xw3
    float* bufB = (float*)alloc((size_t)N_NODES * 256 * 4);  // h1, later h3
    float* bufC = (float*)alloc((size_t)N_NODES * 128 * 4);  // h2
    float* dis  = (float*)alloc(N_NODES * 4);
    int* cnt    = (int*)alloc(N_NODES * 4);
    int* offs   = (int*)alloc(N_NODES * 4);
    int* cursor = (int*)alloc(N_NODES * 4);
    int* bsum   = (int*)alloc(256 * 4);
    int* csr    = (int*)alloc((size_t)E_TRAIN * 4);
    short* Wt1h = (short*)alloc((size_t)128 * 256 * 2);
    short* Wt1l = (short*)alloc((size_t)128 * 256 * 2);
    short* Wt2h = (short*)alloc((size_t)256 * 128 * 2);
    short* Wt2l = (short*)alloc((size_t)256 * 128 * 2);
    short* Wt3h = (short*)alloc((size_t)128 * 64 * 2);
    short* Wt3l = (short*)alloc((size_t)128 * 64 * 2);
    (void)ws_size; (void)n_in; (void)in_sizes; (void)out_size;

    hipMemsetAsync(cnt, 0, N_NODES * 4, stream);
    count_kernel<<<(E_TRAIN + 255) / 256, 256, 0, stream>>>(dst, cnt, E_TRAIN);
    dis_kernel<<<(N_NODES + 255) / 256, 256, 0, stream>>>(cnt, dis, N_NODES);
    int nb = (N_NODES + 255) / 256;  // 196
    scan1_kernel<<<nb, 256, 0, stream>>>(cnt, offs, bsum, N_NODES);
    scan2_kernel<<<1, 256, 0, stream>>>(bsum, nb);
    scan3_kernel<<<nb, 256, 0, stream>>>(offs, bsum, cursor, N_NODES);
    fill_kernel<<<(E_TRAIN + 255) / 256, 256, 0, stream>>>(src, dst, cursor, csr, E_TRAIN);
    // after fill: offs[v] = start, cursor[v] = end

    // split/transpose weights into ws (tiny)
    wsplit_kernel<<<(128 * 256 + 255) / 256, 256, 0, stream>>>(W1, Wt1h, Wt1l, 128, 256);
    wsplit_kernel<<<(256 * 128 + 255) / 256, 256, 0, stream>>>(W2, Wt2h, Wt2l, 256, 128);
    wsplit_kernel<<<(128 * 64 + 255) / 256, 256, 0, stream>>>(W3, Wt3h, Wt3l, 128, 64);

    const int MB = (N_NODES + 127) / 128;     // 391 row tiles
    const int AGG_BLOCKS = (N_NODES + 3) / 4; // 4 waves/block, 1 node/wave

    // layer 1 (agg-first): aggX = agg(x) [F=128]; h1 = relu(aggX @ W1 + b1) [256]
    aggregate_kernel<128, false, false><<<AGG_BLOCKS, 256, 0, stream>>>(
        x, bufA, dis, offs, cursor, csr, nullptr, N_NODES);
    gemm_mfma_kernel<true><<<dim3(MB, 4), 256, 0, stream>>>(
        bufA, Wt1h, Wt1l, b1, bufB, N_NODES, 256, 128);

    // layer 2 (gemm-first): xw2 = h1 @ W2 [128]; h2 = relu(agg(xw2) + b2)
    gemm_mfma_kernel<false><<<dim3(MB, 2), 256, 0, stream>>>(
        bufB, Wt2h, Wt2l, nullptr, bufA, N_NODES, 128, 256);
    aggregate_kernel<128, true, true><<<AGG_BLOCKS, 256, 0, stream>>>(
        bufA, bufC, dis, offs, cursor, csr, b2, N_NODES);

    // layer 3 (gemm-first): xw3 = h2 @ W3 [64]; h3 = agg(xw3) + b3
    gemm_mfma_kernel<false><<<dim3(MB, 1), 256, 0, stream>>>(
        bufC, Wt3h, Wt3l, nullptr, bufA, N_NODES, 64, 128);
    aggregate_kernel<64, false, true><<<AGG_BLOCKS, 256, 0, stream>>>(
        bufA, bufB, dis, offs, cursor, csr, b3, N_NODES);

    // edge dots over h3 (64 features)
    dot_kernel<<<(E_POS + E_NEG + 255) / 256, 256, 0, stream>>>(bufB, pos, neg, out);
}